// Round 3
// baseline (182.503 us; speedup 1.0000x reference)
//
#include <hip/hip_runtime.h>

// x (8,320,320) f32, u (8,12,320,320,2) f32 -> out (8,12,320,320) f32.
#define PP 8
#define FF 12
#define MM 320
#define NN 320

typedef float fvec4 __attribute__((ext_vector_type(4)));

// Each thread handles 4 consecutive pixels in one row (320 % 4 == 0, so a
// 4-group never crosses a row or image boundary).
__global__ __launch_bounds__(256) void warp_fwd_kernel(
    const float* __restrict__ x,
    const fvec4* __restrict__ u4,    // u viewed as fvec4 = 2 pixels' (dx,dy)
    fvec4* __restrict__ out4,
    int total4)                      // total pixels / 4
{
    int g = blockIdx.x * blockDim.x + threadIdx.x;
    if (g >= total4) return;

    int base = g << 2;                    // first pixel index of the group
    int ij = base % (MM * NN);
    int p  = base / (FF * MM * NN);
    int i  = ij / NN;
    int j0 = ij - i * NN;

    // Streaming read of flow: 2x 16B = 4 pixels of (dx,dy). Non-temporal
    // so u doesn't evict the x images from L2.
    fvec4 ua = __builtin_nontemporal_load(&u4[2 * g]);
    fvec4 ub = __builtin_nontemporal_load(&u4[2 * g + 1]);
    float dx[4] = {ua.x, ua.z, ub.x, ub.z};
    float dy[4] = {ua.y, ua.w, ub.y, ub.w};

    const float* __restrict__ img = x + p * (MM * NN);

    float res[4];
#pragma unroll
    for (int k = 0; k < 4; ++k) {
        float sx = (float)(j0 + k) + dx[k];
        float sy = (float)i + dy[k];
        float fx0 = floorf(sx);
        float fy0 = floorf(sy);
        float wx = sx - fx0;
        float wy = sy - fy0;
        int x0i = (int)fx0;
        int y0i = (int)fy0;

        int xc0 = min(max(x0i,     0), NN - 1);
        int xc1 = min(max(x0i + 1, 0), NN - 1);
        int yc0 = min(max(y0i,     0), MM - 1);
        int yc1 = min(max(y0i + 1, 0), MM - 1);
        bool vx0 = (x0i >= 0)     & (x0i < NN);
        bool vx1 = (x0i + 1 >= 0) & (x0i + 1 < NN);
        bool vy0 = (y0i >= 0)     & (y0i < MM);
        bool vy1 = (y0i + 1 >= 0) & (y0i + 1 < MM);

        int r0 = yc0 * NN;
        int r1 = yc1 * NN;
        float v00 = (vy0 & vx0) ? img[r0 + xc0] : 0.0f;
        float v01 = (vy0 & vx1) ? img[r0 + xc1] : 0.0f;
        float v10 = (vy1 & vx0) ? img[r1 + xc0] : 0.0f;
        float v11 = (vy1 & vx1) ? img[r1 + xc1] : 0.0f;

        float omwx = 1.0f - wx;
        float omwy = 1.0f - wy;
        res[k] = (v00 * omwx + v01 * wx) * omwy
               + (v10 * omwx + v11 * wx) * wy;
    }

    fvec4 o = {res[0], res[1], res[2], res[3]};
    __builtin_nontemporal_store(o, &out4[g]);
}

extern "C" void kernel_launch(void* const* d_in, const int* in_sizes, int n_in,
                              void* d_out, int out_size, void* d_ws, size_t ws_size,
                              hipStream_t stream) {
    const float* x = (const float*)d_in[0];
    const fvec4* u = (const fvec4*)d_in[1];
    fvec4* out = (fvec4*)d_out;

    int total4 = out_size >> 2;   // 9,830,400 / 4 = 2,457,600
    int block = 256;
    int grid = (total4 + block - 1) / block;
    warp_fwd_kernel<<<grid, block, 0, stream>>>(x, u, out, total4);
}

// Round 4
// 166.804 us; speedup vs baseline: 1.0941x; 1.0941x over previous
//
#include <hip/hip_runtime.h>

// x (8,320,320) f32, u (8,12,320,320,2) f32 -> out (8,12,320,320) f32.
#define PP 8
#define FF 12
#define MM 320
#define NN 320
#define TILE 64
#define HALO 16
#define LW   (TILE + 2 * HALO)   // 96 staged rows/cols
#define LPITCH (LW + 1)          // 97, breaks pow2/32-multiple bank stride

typedef float fvec4 __attribute__((ext_vector_type(4)));

__global__ __launch_bounds__(256) void warp_tile_kernel(
    const float* __restrict__ x,
    const float* __restrict__ u,
    float* __restrict__ out)
{
    __shared__ float tile[LW * LPITCH];   // 96*97*4 = 37.2 KB

    int pf = blockIdx.z;                  // p*FF + f
    int p  = pf / FF;
    int i0 = blockIdx.y * TILE;
    int j0 = blockIdx.x * TILE;

    const float* __restrict__ img = x + p * (MM * NN);

    // Stage rows [i0-HALO, i0+TILE+HALO) x cols [j0-HALO, j0+TILE+HALO),
    // zero-filled outside the image (matches reference zero-padding).
    for (int idx = threadIdx.x; idx < LW * LW; idx += 256) {
        int r = idx / LW;
        int c = idx - r * LW;
        int gr = i0 - HALO + r;
        int gc = j0 - HALO + c;
        float v = 0.0f;
        if ((unsigned)gr < MM && (unsigned)gc < NN) v = img[gr * NN + gc];
        tile[r * LPITCH + c] = v;
    }
    __syncthreads();

    // Thread layout: 4 consecutive cols x 4 rows (strided by 16) per thread.
    int tcol = (threadIdx.x & 15) * 4;    // 0,4,...,60
    int row0 = (threadIdx.x >> 4);        // 0..15

    const float* __restrict__ ubase = u + (size_t)pf * (MM * NN * 2);
    float* __restrict__ obase = out + (size_t)pf * (MM * NN);

    for (int s = 0; s < 4; ++s) {
        int row = row0 + s * 16;          // 0..63 within tile
        int gi  = i0 + row;               // global row
        int gj  = j0 + tcol;              // global col of first of 4 pixels

        const fvec4* up = (const fvec4*)(ubase + 2 * ((size_t)gi * NN + gj));
        fvec4 ua = __builtin_nontemporal_load(&up[0]);
        fvec4 ub = __builtin_nontemporal_load(&up[1]);
        float dx[4] = {ua.x, ua.z, ub.x, ub.z};
        float dy[4] = {ua.y, ua.w, ub.y, ub.w};

        float res[4];
#pragma unroll
        for (int k = 0; k < 4; ++k) {
            float sx = (float)(gj + k) + dx[k];
            float sy = (float)gi + dy[k];
            float fx0 = floorf(sx);
            float fy0 = floorf(sy);
            float wx = sx - fx0;
            float wy = sy - fy0;
            int x0i = (int)fx0;
            int y0i = (int)fy0;

            int lx = x0i - (j0 - HALO);   // LDS col of left corner
            int ly = y0i - (i0 - HALO);   // LDS row of top corner

            float v00, v01, v10, v11;
            if ((unsigned)lx < (LW - 1) && (unsigned)ly < (LW - 1)) {
                const float* t0 = &tile[ly * LPITCH + lx];
                v00 = t0[0];
                v01 = t0[1];
                v10 = t0[LPITCH];
                v11 = t0[LPITCH + 1];
            } else {
                // Rare fallback (|flow| > 15): predicated global gather.
                int xc0 = min(max(x0i,     0), NN - 1);
                int xc1 = min(max(x0i + 1, 0), NN - 1);
                int yc0 = min(max(y0i,     0), MM - 1);
                int yc1 = min(max(y0i + 1, 0), MM - 1);
                bool vx0 = (x0i >= 0)     & (x0i < NN);
                bool vx1 = (x0i + 1 >= 0) & (x0i + 1 < NN);
                bool vy0 = (y0i >= 0)     & (y0i < MM);
                bool vy1 = (y0i + 1 >= 0) & (y0i + 1 < MM);
                int r0 = yc0 * NN;
                int r1 = yc1 * NN;
                v00 = (vy0 & vx0) ? img[r0 + xc0] : 0.0f;
                v01 = (vy0 & vx1) ? img[r0 + xc1] : 0.0f;
                v10 = (vy1 & vx0) ? img[r1 + xc0] : 0.0f;
                v11 = (vy1 & vx1) ? img[r1 + xc1] : 0.0f;
            }

            float omwx = 1.0f - wx;
            float omwy = 1.0f - wy;
            res[k] = (v00 * omwx + v01 * wx) * omwy
                   + (v10 * omwx + v11 * wx) * wy;
        }

        fvec4 o = {res[0], res[1], res[2], res[3]};
        __builtin_nontemporal_store(o, (fvec4*)(obase + (size_t)gi * NN + gj));
    }
}

extern "C" void kernel_launch(void* const* d_in, const int* in_sizes, int n_in,
                              void* d_out, int out_size, void* d_ws, size_t ws_size,
                              hipStream_t stream) {
    const float* x = (const float*)d_in[0];
    const float* u = (const float*)d_in[1];
    float* out = (float*)d_out;

    dim3 grid(NN / TILE, MM / TILE, PP * FF);   // 5 x 5 x 96 = 2400 blocks
    dim3 block(256);
    warp_tile_kernel<<<grid, block, 0, stream>>>(x, u, out);
}

// Round 5
// 136.135 us; speedup vs baseline: 1.3406x; 1.2253x over previous
//
#include <hip/hip_runtime.h>

// x (8,320,320) f32, u (8,12,320,320,2) f32 -> out (8,12,320,320) f32.
#define PP 8
#define FF 12
#define MM 320
#define NN 320
#define TILE 64
#define HALO 16
#define LW   (TILE + 2 * HALO)   // 96 staged rows/cols
#define LPITCH 100               // 100*4=400 B row pitch: 16B-aligned, bank-shift 4/row

typedef float fvec4 __attribute__((ext_vector_type(4)));

__global__ __launch_bounds__(512, 8) void warp_tile_kernel(
    const float* __restrict__ x,
    const float* __restrict__ u,
    float* __restrict__ out)
{
    __shared__ float tile[LW * LPITCH];   // 96*100*4 = 38,400 B -> 4 blocks/CU

    int pf = blockIdx.z;                  // p*FF + f
    int p  = pf / FF;
    int i0 = blockIdx.y * TILE;
    int j0 = blockIdx.x * TILE;

    const float* __restrict__ img = x + p * (MM * NN);

    // Thread layout: 4 consecutive cols x 2 row-sets (strided by 32) per thread.
    int tcol = ((int)threadIdx.x & 15) * 4;   // 0..60
    int row0 = ((int)threadIdx.x >> 4);       // 0..31

    const float* __restrict__ ubase = u + (size_t)pf * (MM * NN * 2);
    float* __restrict__ obase = out + (size_t)pf * (MM * NN);

    // Hoist flow loads above staging so their latency overlaps it.
    fvec4 ua[2], ub[2];
#pragma unroll
    for (int s = 0; s < 2; ++s) {
        int gi = i0 + row0 + s * 32;
        const fvec4* up = (const fvec4*)(ubase + 2 * ((size_t)gi * NN + (j0 + tcol)));
        ua[s] = __builtin_nontemporal_load(&up[0]);
        ub[s] = __builtin_nontemporal_load(&up[1]);
    }

    // Stage rows [i0-HALO, i0+TILE+HALO) x cols [j0-HALO, j0+TILE+HALO),
    // zero-filled outside (matches reference). float4 granularity: col groups
    // are 4-aligned vs the image (j0%64==0, HALO=16, NN%4==0), so a group is
    // entirely in or out of column range.
    for (int idx = threadIdx.x; idx < LW * (LW / 4); idx += 512) {
        int r  = idx / (LW / 4);
        int c4 = idx - r * (LW / 4);
        int gr = i0 - HALO + r;
        int gc = j0 - HALO + c4 * 4;
        fvec4 v = {0.0f, 0.0f, 0.0f, 0.0f};
        if ((unsigned)gr < MM && (unsigned)gc < NN)
            v = *(const fvec4*)(img + gr * NN + gc);
        *(fvec4*)(tile + r * LPITCH + c4 * 4) = v;
    }
    __syncthreads();

#pragma unroll
    for (int s = 0; s < 2; ++s) {
        int gi = i0 + row0 + s * 32;      // global row
        int gj = j0 + tcol;               // global col of first of 4 pixels

        float dx[4] = {ua[s].x, ua[s].z, ub[s].x, ub[s].z};
        float dy[4] = {ua[s].y, ua[s].w, ub[s].y, ub[s].w};

        float res[4];
#pragma unroll
        for (int k = 0; k < 4; ++k) {
            float sx = (float)(gj + k) + dx[k];
            float sy = (float)gi + dy[k];
            float fx0 = floorf(sx);
            float fy0 = floorf(sy);
            float wx = sx - fx0;
            float wy = sy - fy0;
            int x0i = (int)fx0;
            int y0i = (int)fy0;

            int lx = x0i - (j0 - HALO);   // LDS col of left corner
            int ly = y0i - (i0 - HALO);   // LDS row of top corner

            float v00, v01, v10, v11;
            if ((unsigned)lx < (LW - 1) && (unsigned)ly < (LW - 1)) {
                const float* t0 = &tile[ly * LPITCH + lx];
                v00 = t0[0];
                v01 = t0[1];
                v10 = t0[LPITCH];
                v11 = t0[LPITCH + 1];
            } else {
                // Rare (|flow| > 15 px): predicated global gather.
                int xc0 = min(max(x0i,     0), NN - 1);
                int xc1 = min(max(x0i + 1, 0), NN - 1);
                int yc0 = min(max(y0i,     0), MM - 1);
                int yc1 = min(max(y0i + 1, 0), MM - 1);
                bool vx0 = (x0i >= 0)     & (x0i < NN);
                bool vx1 = (x0i + 1 >= 0) & (x0i + 1 < NN);
                bool vy0 = (y0i >= 0)     & (y0i < MM);
                bool vy1 = (y0i + 1 >= 0) & (y0i + 1 < MM);
                int r0 = yc0 * NN;
                int r1 = yc1 * NN;
                v00 = (vy0 & vx0) ? img[r0 + xc0] : 0.0f;
                v01 = (vy0 & vx1) ? img[r0 + xc1] : 0.0f;
                v10 = (vy1 & vx0) ? img[r1 + xc0] : 0.0f;
                v11 = (vy1 & vx1) ? img[r1 + xc1] : 0.0f;
            }

            float omwx = 1.0f - wx;
            float omwy = 1.0f - wy;
            res[k] = (v00 * omwx + v01 * wx) * omwy
                   + (v10 * omwx + v11 * wx) * wy;
        }

        fvec4 o = {res[0], res[1], res[2], res[3]};
        __builtin_nontemporal_store(o, (fvec4*)(obase + (size_t)gi * NN + gj));
    }
}

extern "C" void kernel_launch(void* const* d_in, const int* in_sizes, int n_in,
                              void* d_out, int out_size, void* d_ws, size_t ws_size,
                              hipStream_t stream) {
    const float* x = (const float*)d_in[0];
    const float* u = (const float*)d_in[1];
    float* out = (float*)d_out;

    dim3 grid(NN / TILE, MM / TILE, PP * FF);   // 5 x 5 x 96 = 2400 blocks
    dim3 block(512);
    warp_tile_kernel<<<grid, block, 0, stream>>>(x, u, out);
}

// Round 6
// 135.722 us; speedup vs baseline: 1.3447x; 1.0030x over previous
//
#include <hip/hip_runtime.h>

// x (8,320,320) f32, u (8,12,320,320,2) f32 -> out (8,12,320,320) f32.
#define PP 8
#define FF 12
#define MM 320
#define NN 320
#define TILE 64
#define HALO 16
#define LW   (TILE + 2 * HALO)   // 96 staged rows/cols
#define LPITCH 100               // 400 B row pitch: 16B-aligned
#define FPB  3                   // frames per block (12 = 4 groups of 3)

typedef float fvec4 __attribute__((ext_vector_type(4)));

__global__ __launch_bounds__(512, 8) void warp_tile_kernel(
    const float* __restrict__ x,
    const float* __restrict__ u,
    float* __restrict__ out)
{
    __shared__ float tile[LW * LPITCH];   // 38,400 B -> 4 blocks/CU

    int zz = blockIdx.z;                  // p * 4 + fgroup
    int p  = zz >> 2;
    int f0 = (zz & 3) * FPB;
    int i0 = blockIdx.y * TILE;
    int j0 = blockIdx.x * TILE;

    const float* __restrict__ img = x + p * (MM * NN);

    // Stage once per block: rows [i0-HALO, i0+TILE+HALO) x cols
    // [j0-HALO, j0+TILE+HALO), zero outside (reference zero-padding).
    // Col 4-groups are 4-aligned vs the image, so each is fully in or out.
    for (int idx = threadIdx.x; idx < LW * (LW / 4); idx += 512) {
        int r  = idx / (LW / 4);
        int c4 = idx - r * (LW / 4);
        int gr = i0 - HALO + r;
        int gc = j0 - HALO + c4 * 4;
        fvec4 v = {0.0f, 0.0f, 0.0f, 0.0f};
        if ((unsigned)gr < MM && (unsigned)gc < NN)
            v = *(const fvec4*)(img + gr * NN + gc);
        *(fvec4*)(tile + r * LPITCH + c4 * 4) = v;
    }
    __syncthreads();

    // Thread layout: 4 consecutive cols x 2 row-sets (strided by 32).
    int tcol = ((int)threadIdx.x & 15) * 4;   // 0..60
    int row0 = ((int)threadIdx.x >> 4);       // 0..31

    for (int ff = 0; ff < FPB; ++ff) {
        int pf = p * FF + (f0 + ff);
        const float* __restrict__ ubase = u + (size_t)pf * (MM * NN * 2);
        float* __restrict__ obase = out + (size_t)pf * (MM * NN);

#pragma unroll
        for (int s = 0; s < 2; ++s) {
            int gi = i0 + row0 + s * 32;
            int gj = j0 + tcol;

            const fvec4* up = (const fvec4*)(ubase + 2 * ((size_t)gi * NN + gj));
            fvec4 ua = __builtin_nontemporal_load(&up[0]);
            fvec4 ub = __builtin_nontemporal_load(&up[1]);
            float dx[4] = {ua.x, ua.z, ub.x, ub.z};
            float dy[4] = {ua.y, ua.w, ub.y, ub.w};

            float res[4];
#pragma unroll
            for (int k = 0; k < 4; ++k) {
                float sx = (float)(gj + k) + dx[k];
                float sy = (float)gi + dy[k];
                float fx0 = floorf(sx);
                float fy0 = floorf(sy);
                float wx = sx - fx0;
                float wy = sy - fy0;
                int x0i = (int)fx0;
                int y0i = (int)fy0;

                int lx = x0i - (j0 - HALO);
                int ly = y0i - (i0 - HALO);

                float v00, v01, v10, v11;
                if ((unsigned)lx < (LW - 1) && (unsigned)ly < (LW - 1)) {
                    const float* t0 = &tile[ly * LPITCH + lx];
                    v00 = t0[0];
                    v01 = t0[1];
                    v10 = t0[LPITCH];
                    v11 = t0[LPITCH + 1];
                } else {
                    // Rare (|flow| > 15 px): predicated global gather.
                    int xc0 = min(max(x0i,     0), NN - 1);
                    int xc1 = min(max(x0i + 1, 0), NN - 1);
                    int yc0 = min(max(y0i,     0), MM - 1);
                    int yc1 = min(max(y0i + 1, 0), MM - 1);
                    bool vx0 = (x0i >= 0)     & (x0i < NN);
                    bool vx1 = (x0i + 1 >= 0) & (x0i + 1 < NN);
                    bool vy0 = (y0i >= 0)     & (y0i < MM);
                    bool vy1 = (y0i + 1 >= 0) & (y0i + 1 < MM);
                    int r0 = yc0 * NN;
                    int r1 = yc1 * NN;
                    v00 = (vy0 & vx0) ? img[r0 + xc0] : 0.0f;
                    v01 = (vy0 & vx1) ? img[r0 + xc1] : 0.0f;
                    v10 = (vy1 & vx0) ? img[r1 + xc0] : 0.0f;
                    v11 = (vy1 & vx1) ? img[r1 + xc1] : 0.0f;
                }

                // 3-lerp form: 6 FMA-class ops.
                float vt = fmaf(wx, v01 - v00, v00);
                float vb = fmaf(wx, v11 - v10, v10);
                res[k] = fmaf(wy, vb - vt, vt);
            }

            fvec4 o = {res[0], res[1], res[2], res[3]};
            __builtin_nontemporal_store(o, (fvec4*)(obase + (size_t)gi * NN + gj));
        }
    }
}

extern "C" void kernel_launch(void* const* d_in, const int* in_sizes, int n_in,
                              void* d_out, int out_size, void* d_ws, size_t ws_size,
                              hipStream_t stream) {
    const float* x = (const float*)d_in[0];
    const float* u = (const float*)d_in[1];
    float* out = (float*)d_out;

    dim3 grid(NN / TILE, MM / TILE, PP * (FF / FPB));  // 5 x 5 x 32 = 800 blocks
    dim3 block(512);
    warp_tile_kernel<<<grid, block, 0, stream>>>(x, u, out);
}

// Round 7
// 134.587 us; speedup vs baseline: 1.3560x; 1.0084x over previous
//
#include <hip/hip_runtime.h>

// x (8,320,320) f32, u (8,12,320,320,2) f32 -> out (8,12,320,320) f32.
#define PP 8
#define FF 12
#define MM 320
#define NN 320
#define TILE 64
#define HALO 16
#define LW   (TILE + 2 * HALO)   // 96 staged rows/cols
#define LPITCH 100               // 400 B row pitch: 16B-aligned
#define FPB  2                   // frames per block (12 = 6 groups of 2)

typedef float fvec4 __attribute__((ext_vector_type(4)));

__global__ __launch_bounds__(512, 8) void warp_tile_kernel(
    const float* __restrict__ x,
    const float* __restrict__ u,
    float* __restrict__ out)
{
    __shared__ float tile[LW * LPITCH];   // 38,400 B -> 4 blocks/CU

    int zz = blockIdx.z;                  // p * 6 + fgroup
    int p  = zz / (FF / FPB);
    int f0 = (zz % (FF / FPB)) * FPB;
    int i0 = blockIdx.y * TILE;
    int j0 = blockIdx.x * TILE;

    const float* __restrict__ img = x + p * (MM * NN);

    // Stage once per block: rows [i0-HALO, i0+TILE+HALO) x cols
    // [j0-HALO, j0+TILE+HALO), zero outside (reference zero-padding).
    // Col 4-groups are 4-aligned vs the image, so each is fully in or out.
    for (int idx = threadIdx.x; idx < LW * (LW / 4); idx += 512) {
        int r  = idx / (LW / 4);
        int c4 = idx - r * (LW / 4);
        int gr = i0 - HALO + r;
        int gc = j0 - HALO + c4 * 4;
        fvec4 v = {0.0f, 0.0f, 0.0f, 0.0f};
        if ((unsigned)gr < MM && (unsigned)gc < NN)
            v = *(const fvec4*)(img + gr * NN + gc);
        *(fvec4*)(tile + r * LPITCH + c4 * 4) = v;
    }
    __syncthreads();

    // Thread layout: 4 consecutive cols x 2 row-sets (strided by 32).
    int tcol = ((int)threadIdx.x & 15) * 4;   // 0..60
    int row0 = ((int)threadIdx.x >> 4);       // 0..31

#pragma unroll
    for (int ff = 0; ff < FPB; ++ff) {
        int pf = p * FF + (f0 + ff);
        const float* __restrict__ ubase = u + (size_t)pf * (MM * NN * 2);
        float* __restrict__ obase = out + (size_t)pf * (MM * NN);

#pragma unroll
        for (int s = 0; s < 2; ++s) {
            int gi = i0 + row0 + s * 32;
            int gj = j0 + tcol;

            const fvec4* up = (const fvec4*)(ubase + 2 * ((size_t)gi * NN + gj));
            fvec4 ua = __builtin_nontemporal_load(&up[0]);
            fvec4 ub = __builtin_nontemporal_load(&up[1]);
            float dx[4] = {ua.x, ua.z, ub.x, ub.z};
            float dy[4] = {ua.y, ua.w, ub.y, ub.w};

            float res[4];
#pragma unroll
            for (int k = 0; k < 4; ++k) {
                float sx = (float)(gj + k) + dx[k];
                float sy = (float)gi + dy[k];
                float fx0 = floorf(sx);
                float fy0 = floorf(sy);
                float wx = sx - fx0;
                float wy = sy - fy0;
                int x0i = (int)fx0;
                int y0i = (int)fy0;

                int lx = x0i - (j0 - HALO);
                int ly = y0i - (i0 - HALO);

                float v00, v01, v10, v11;
                if ((unsigned)lx < (LW - 1) && (unsigned)ly < (LW - 1)) {
                    const float* t0 = &tile[ly * LPITCH + lx];
                    v00 = t0[0];
                    v01 = t0[1];
                    v10 = t0[LPITCH];
                    v11 = t0[LPITCH + 1];
                } else {
                    // Rare (|flow| beyond halo): predicated global gather.
                    int xc0 = min(max(x0i,     0), NN - 1);
                    int xc1 = min(max(x0i + 1, 0), NN - 1);
                    int yc0 = min(max(y0i,     0), MM - 1);
                    int yc1 = min(max(y0i + 1, 0), MM - 1);
                    bool vx0 = (x0i >= 0)     & (x0i < NN);
                    bool vx1 = (x0i + 1 >= 0) & (x0i + 1 < NN);
                    bool vy0 = (y0i >= 0)     & (y0i < MM);
                    bool vy1 = (y0i + 1 >= 0) & (y0i + 1 < MM);
                    int r0 = yc0 * NN;
                    int r1 = yc1 * NN;
                    v00 = (vy0 & vx0) ? img[r0 + xc0] : 0.0f;
                    v01 = (vy0 & vx1) ? img[r0 + xc1] : 0.0f;
                    v10 = (vy1 & vx0) ? img[r1 + xc0] : 0.0f;
                    v11 = (vy1 & vx1) ? img[r1 + xc1] : 0.0f;
                }

                // 3-lerp form: 6 FMA-class ops.
                float vt = fmaf(wx, v01 - v00, v00);
                float vb = fmaf(wx, v11 - v10, v10);
                res[k] = fmaf(wy, vb - vt, vt);
            }

            fvec4 o = {res[0], res[1], res[2], res[3]};
            __builtin_nontemporal_store(o, (fvec4*)(obase + (size_t)gi * NN + gj));
        }
    }
}

extern "C" void kernel_launch(void* const* d_in, const int* in_sizes, int n_in,
                              void* d_out, int out_size, void* d_ws, size_t ws_size,
                              hipStream_t stream) {
    const float* x = (const float*)d_in[0];
    const float* u = (const float*)d_in[1];
    float* out = (float*)d_out;

    dim3 grid(NN / TILE, MM / TILE, PP * (FF / FPB));  // 5 x 5 x 48 = 1200 blocks
    dim3 block(512);
    warp_tile_kernel<<<grid, block, 0, stream>>>(x, u, out);
}

// Round 8
// 134.121 us; speedup vs baseline: 1.3607x; 1.0035x over previous
//
#include <hip/hip_runtime.h>
#include <hip/hip_fp16.h>

// x (8,320,320) f32, u (8,12,320,320,2) f32 -> out (8,12,320,320) f32.
#define PP 8
#define FF 12
#define MM 320
#define NN 320
#define TILE 64
#define HALO 16
#define LW   (TILE + 2 * HALO)   // 96 staged rows/cols
#define PW   49                  // 32-bit words per LDS row (48 data + 1 pad)
#define FPB  2                   // frames per block

typedef float fvec4 __attribute__((ext_vector_type(4)));

// Tile stored as fp16 pairs in TWO copies:
//   hA[r][c] = ( px[2c],   px[2c+1] )   c in [0,48)
//   hB[r][c] = ( px[2c+1], px[2c+2] )
// so the horizontal corner pair at any column lx is ONE aligned 32-bit word:
//   even lx -> hA[r][lx/2], odd lx -> hB[r][lx/2]; row below at +PW words.
__global__ __launch_bounds__(512, 8) void warp_tile_kernel(
    const float* __restrict__ x,
    const float* __restrict__ u,
    float* __restrict__ out)
{
    __shared__ unsigned int hA[LW * PW];   // 18,816 B
    __shared__ unsigned int hB[LW * PW];   // total 37,632 B -> 4 blocks/CU

    int zz = blockIdx.z;                   // p * 6 + fgroup
    int p  = zz / (FF / FPB);
    int f0 = (zz % (FF / FPB)) * FPB;
    int i0 = blockIdx.y * TILE;
    int j0 = blockIdx.x * TILE;

    const float* __restrict__ img = x + p * (MM * NN);

    // Phase 1: stage copy A (zero outside image; col 4-groups are aligned so
    // each is fully in or out).
    for (int idx = threadIdx.x; idx < LW * (LW / 4); idx += 512) {
        int r  = idx / (LW / 4);
        int c4 = idx - r * (LW / 4);
        int gr = i0 - HALO + r;
        int gc = j0 - HALO + c4 * 4;
        fvec4 v = {0.0f, 0.0f, 0.0f, 0.0f};
        if ((unsigned)gr < MM && (unsigned)gc < NN)
            v = *(const fvec4*)(img + gr * NN + gc);
        __half2 w0 = __floats2half2_rn(v.x, v.y);
        __half2 w1 = __floats2half2_rn(v.z, v.w);
        unsigned int* dst = &hA[r * PW + c4 * 2];
        dst[0] = *(unsigned int*)&w0;
        dst[1] = *(unsigned int*)&w1;
    }
    __syncthreads();

    // Phase 2: copy B = funnel shift of adjacent A words.
    // (c=47 reads the pad word hA[r*PW+48] — in-bounds, value never consumed.)
    for (int idx = threadIdx.x; idx < LW * (LW / 2); idx += 512) {
        int r = idx / (LW / 2);
        int c = idx - r * (LW / 2);
        unsigned int a0 = hA[r * PW + c];
        unsigned int a1 = hA[r * PW + c + 1];
        hB[r * PW + c] = __builtin_amdgcn_alignbit(a1, a0, 16);
    }
    __syncthreads();

    // Thread layout: 4 consecutive cols x 2 row-sets (strided by 32).
    int tcol = ((int)threadIdx.x & 15) * 4;   // 0..60
    int row0 = ((int)threadIdx.x >> 4);       // 0..31

#pragma unroll
    for (int ff = 0; ff < FPB; ++ff) {
        int pf = p * FF + (f0 + ff);
        const float* __restrict__ ubase = u + (size_t)pf * (MM * NN * 2);
        float* __restrict__ obase = out + (size_t)pf * (MM * NN);

#pragma unroll
        for (int s = 0; s < 2; ++s) {
            int gi = i0 + row0 + s * 32;
            int gj = j0 + tcol;

            const fvec4* up = (const fvec4*)(ubase + 2 * ((size_t)gi * NN + gj));
            fvec4 ua = up[0];
            fvec4 ub = up[1];
            float dx[4] = {ua.x, ua.z, ub.x, ub.z};
            float dy[4] = {ua.y, ua.w, ub.y, ub.w};

            float res[4];
#pragma unroll
            for (int k = 0; k < 4; ++k) {
                float sx = (float)(gj + k) + dx[k];
                float sy = (float)gi + dy[k];
                float fx0 = floorf(sx);
                float fy0 = floorf(sy);
                float wx = sx - fx0;
                float wy = sy - fy0;
                int x0i = (int)fx0;
                int y0i = (int)fy0;

                int lx = x0i - (j0 - HALO);
                int ly = y0i - (i0 - HALO);

                float v00, v01, v10, v11;
                if ((unsigned)lx < (LW - 1) && (unsigned)ly < (LW - 1)) {
                    const unsigned int* base = (lx & 1) ? hB : hA;
                    int w = ly * PW + (lx >> 1);
                    unsigned int t0 = base[w];        // (v00, v01)
                    unsigned int t1 = base[w + PW];   // (v10, v11)
                    float2 r0 = __half22float2(*(const __half2*)&t0);
                    float2 r1 = __half22float2(*(const __half2*)&t1);
                    v00 = r0.x; v01 = r0.y;
                    v10 = r1.x; v11 = r1.y;
                } else {
                    // Rare (|flow| beyond halo): predicated global gather (fp32).
                    int xc0 = min(max(x0i,     0), NN - 1);
                    int xc1 = min(max(x0i + 1, 0), NN - 1);
                    int yc0 = min(max(y0i,     0), MM - 1);
                    int yc1 = min(max(y0i + 1, 0), MM - 1);
                    bool vx0 = (x0i >= 0)     & (x0i < NN);
                    bool vx1 = (x0i + 1 >= 0) & (x0i + 1 < NN);
                    bool vy0 = (y0i >= 0)     & (y0i < MM);
                    bool vy1 = (y0i + 1 >= 0) & (y0i + 1 < MM);
                    int r0i = yc0 * NN;
                    int r1i = yc1 * NN;
                    v00 = (vy0 & vx0) ? img[r0i + xc0] : 0.0f;
                    v01 = (vy0 & vx1) ? img[r0i + xc1] : 0.0f;
                    v10 = (vy1 & vx0) ? img[r1i + xc0] : 0.0f;
                    v11 = (vy1 & vx1) ? img[r1i + xc1] : 0.0f;
                }

                float vt = fmaf(wx, v01 - v00, v00);
                float vb = fmaf(wx, v11 - v10, v10);
                res[k] = fmaf(wy, vb - vt, vt);
            }

            fvec4 o = {res[0], res[1], res[2], res[3]};
            __builtin_nontemporal_store(o, (fvec4*)(obase + (size_t)gi * NN + gj));
        }
    }
}

extern "C" void kernel_launch(void* const* d_in, const int* in_sizes, int n_in,
                              void* d_out, int out_size, void* d_ws, size_t ws_size,
                              hipStream_t stream) {
    const float* x = (const float*)d_in[0];
    const float* u = (const float*)d_in[1];
    float* out = (float*)d_out;

    dim3 grid(NN / TILE, MM / TILE, PP * (FF / FPB));  // 5 x 5 x 48 = 1200 blocks
    dim3 block(512);
    warp_tile_kernel<<<grid, block, 0, stream>>>(x, u, out);
}